// Round 4
// baseline (688.900 us; speedup 1.0000x reference)
//
#include <hip/hip_runtime.h>
#include <stdint.h>

#define AS1 __attribute__((address_space(1)))
#define AS3 __attribute__((address_space(3)))

typedef unsigned short US;
typedef __bf16 bf16x8 __attribute__((ext_vector_type(8)));
typedef float f32x4 __attribute__((ext_vector_type(4)));
typedef int intx4 __attribute__((ext_vector_type(4)));

static constexpr int Bsz = 16384;
static constexpr int DIN = 512;
static constexpr int DH  = 1024;
static constexpr int LDA = 2560;   // Ab row: [h(1024) | x(512) | s(1024)]
static constexpr int LDR = 1536;   // RH row: [r*h(1024) | x(512)]

__device__ __forceinline__ US f2bf(float f) {
  unsigned u = __float_as_uint(f);
  u += 0x7fffu + ((u >> 16) & 1u);          // RNE
  return (US)(u >> 16);
}
__device__ __forceinline__ float bf2f(US u) { return __uint_as_float(((unsigned)u) << 16); }
__device__ __forceinline__ float sigm(float x) { return 1.f / (1.f + __expf(-x)); }
__device__ __forceinline__ float tanh_f(float x) { return 1.f - 2.f / (1.f + __expf(2.f * x)); }

// ds_read_b128 via inline asm: invisible to the backend waitcnt pass, so the
// K-loop's only waits are the hand-placed counted vmcnt / lgkmcnt (HK/m201).
__device__ __forceinline__ intx4 dsr128(unsigned addr) {
  intx4 r;
  asm volatile("ds_read_b128 %0, %1" : "=v"(r) : "v"(addr));
  return r;
}

#define SBAR  asm volatile("s_barrier")
#define SB0   __builtin_amdgcn_sched_barrier(0)
#define LGKM0 { asm volatile("s_waitcnt lgkmcnt(0)"); __builtin_amdgcn_sched_barrier(0); }

// ---------- convert kernels ----------
__global__ void pack_A(const float* __restrict__ h, const float* __restrict__ x,
                       US* __restrict__ Ab, US* __restrict__ RHx) {
  const int total = Bsz * 384;              // 1536 cols / 4 per item
  for (int idx = blockIdx.x * blockDim.x + threadIdx.x; idx < total;
       idx += gridDim.x * blockDim.x) {
    int row = idx / 384;
    int c = (idx - row * 384) * 4;
    const float* src = (c < DH) ? (h + (size_t)row * DH + c)
                                : (x + (size_t)row * DIN + (c - DH));
    float4 v = *(const float4*)src;
    ushort4 o;
    o.x = f2bf(v.x); o.y = f2bf(v.y); o.z = f2bf(v.z); o.w = f2bf(v.w);
    *(ushort4*)(Ab + (size_t)row * LDA + c) = o;
    if (c >= DH) *(ushort4*)(RHx + (size_t)row * LDR + c) = o;
  }
}

struct WSlot { const float* src; US* dst; int n4; int ksh; int ld; int co; };
struct WBatch { WSlot s[11]; };
__global__ void conv_w(WBatch b) {
  WSlot sl = b.s[blockIdx.y];   // uniform per block
  const int mask = (1 << sl.ksh) - 1;
  for (int i = blockIdx.x * blockDim.x + threadIdx.x; i < sl.n4;
       i += gridDim.x * blockDim.x) {
    float4 v = *(const float4*)(sl.src + (size_t)i * 4);
    ushort4 o;
    o.x = f2bf(v.x); o.y = f2bf(v.y); o.z = f2bf(v.z); o.w = f2bf(v.w);
    int r = i >> sl.ksh;
    int cc = (i & mask) * 4;
    *(ushort4*)(sl.dst + (size_t)r * sl.ld + sl.co + cc) = o;
  }
}

// ---------- 256x256 8-phase GEMM, C = A @ W^T, fused epilogue ----------
// 8 waves (2Mx4N), BK=64, dbuf LDS, 2-tiles-ahead staging, counted vmcnt(8)
// at tile boundaries only. All K-loop LDS reads are inline-asm ds_read_b128
// with one lgkmcnt(0) per phase; barriers are raw asm s_barrier; sched_barrier(0)
// walls pin phase membership so the vmcnt accounting is exact.
//
// Staging legality (R3 post-mortem — derived from ACTUAL read rows):
//   b0/b1 are 32-row stripes: READ_B(*,nh) reads Bs rows wc*64+nh*32+{0..31},
//   so ALL Bs[cur] rows are last read by end of phase 1 -> stage B(t+2) at p2.
//   READ_A(mh) reads As rows wr*128+mh*64+{0..63}: both A halves are touched
//   in phases 0 AND 2 -> stage A(t+2) at p3 only.
//   Every wave passes the phase-end barrier only after its LGKM0 retired its
//   reads, so no DMA issued in a later phase can land on unread data.
// Boundary: outstanding = t+1's 8 (older) + t+2's 8 -> vmcnt(8) retires t+1.
//
// EPI: 0 = fused s/r/z (gate = nIdx>>2)   3 = htilde(tanh)   4 = T + combine
template <int EPI, int NBLK>
__global__ __launch_bounds__(512, 2) void gemm8(
    const US* __restrict__ A, int lda,
    const US* __restrict__ W, int ldw, int nt,
    const float* __restrict__ bias0, const float* __restrict__ bias1,
    const float* __restrict__ bias2,
    const void* aux0, const void* aux1, const void* aux2,
    void* out0, int ldo0, void* out1, void* out2) {
  __shared__ __align__(16) US As[2][256 * 64];
  __shared__ __align__(16) US Bs[2][256 * 64];

  const int tid  = threadIdx.x;
  const int lane = tid & 63;
  const int w    = tid >> 6;          // wave 0..7
  const int wr   = w >> 2;            // m half (128 rows)
  const int wc   = w & 3;             // n quarter (64 cols)
  const int quad = lane >> 4, l15 = lane & 15;
  const int sw8  = l15 & 7;
  const int lrow = lane >> 3;
  const int scc  = (lane & 7) ^ (lrow & 7);

  // XCD-aware bijective swizzle: XCD c owns m-blocks [c*8, c*8+8) x all NBLK
  // n-peers -> A tiles fetched ~once per XCD L2.
  const int p = blockIdx.x;
  const int c = p & 7, q = p >> 3;
  const int nIdx = q % NBLK, mIdx = c * 8 + q / NBLK;
  const int mBase = mIdx * 256, nBase = nIdx * 256;

  f32x4 acc[8][4];
#pragma unroll
  for (int i = 0; i < 8; i++)
#pragma unroll
    for (int j = 0; j < 4; j++) acc[i][j] = f32x4{0.f, 0.f, 0.f, 0.f};

  // LDS byte bases (low 32 bits of the generic pointer = LDS offset)
  const unsigned aBase = (unsigned)(uintptr_t)&As[0][0];
  const unsigned bBase = (unsigned)(uintptr_t)&Bs[0][0];
  const unsigned arB = (unsigned)((wr * 128 + l15) * 128);
  const unsigned brB = (unsigned)((wc * 64 + l15) * 128);
  const unsigned kc0 = (unsigned)((quad ^ sw8) * 16);

  const size_t aRowS = (size_t)(mBase + w * 8 + lrow) * lda;
  const size_t wRowS = (size_t)(nBase + w * 8 + lrow) * ldw;
  const int sccOff = scc * 8;

#define STAGE_A(d, hh, co)                                                       \
  { const US* g = A + aRowS + (size_t)(hh) * 128 * lda + (co) + sccOff;          \
    __builtin_amdgcn_global_load_lds((AS1 const void*)g,                         \
        (AS3 void*)&As[d][((hh)*128 + w * 8) * 64], 16, 0, 0);                   \
    __builtin_amdgcn_global_load_lds((AS1 const void*)(g + (size_t)64 * lda),    \
        (AS3 void*)&As[d][((hh)*128 + 64 + w * 8) * 64], 16, 0, 0); }
#define STAGE_B(d, hh, co)                                                       \
  { const US* g = W + wRowS + (size_t)(hh) * 128 * ldw + (co) + sccOff;          \
    __builtin_amdgcn_global_load_lds((AS1 const void*)g,                         \
        (AS3 void*)&Bs[d][((hh)*128 + w * 8) * 64], 16, 0, 0);                   \
    __builtin_amdgcn_global_load_lds((AS1 const void*)(g + (size_t)64 * ldw),    \
        (AS3 void*)&Bs[d][((hh)*128 + 64 + w * 8) * 64], 16, 0, 0); }

#define READ_A(mh)                                                               \
  _Pragma("unroll")                                                              \
  for (int i = 0; i < 4; ++i)                                                    \
    _Pragma("unroll")                                                            \
    for (int ks = 0; ks < 2; ++ks)                                               \
      af[i][ks] = dsr128(aC + arB + (mh)*8192u + (unsigned)i * 2048u +           \
                         (kc0 ^ (unsigned)(ks << 6)));
#define READ_B(BSET, nh)                                                         \
  _Pragma("unroll")                                                              \
  for (int j = 0; j < 2; ++j)                                                    \
    _Pragma("unroll")                                                            \
    for (int ks = 0; ks < 2; ++ks)                                               \
      BSET[j][ks] = dsr128(bC + brB + (nh)*4096u + (unsigned)j * 2048u +         \
                           (kc0 ^ (unsigned)(ks << 6)));
#define MFMA_Q(mh, BSET, nh)                                                     \
  _Pragma("unroll")                                                              \
  for (int ks = 0; ks < 2; ++ks)                                                 \
    _Pragma("unroll")                                                            \
    for (int i = 0; i < 4; ++i)                                                  \
      _Pragma("unroll")                                                          \
      for (int j = 0; j < 2; ++j)                                                \
        acc[(mh)*4 + i][(nh)*2 + j] = __builtin_amdgcn_mfma_f32_16x16x32_bf16(   \
            __builtin_bit_cast(bf16x8, af[i][ks]),                               \
            __builtin_bit_cast(bf16x8, BSET[j][ks]),                             \
            acc[(mh)*4 + i][(nh)*2 + j], 0, 0, 0);

  // ---- prologue: tiles 0 and 1 fully staged; retire tile 0, keep 8 in flight
  STAGE_B(0, 0, 0); STAGE_B(0, 1, 0); STAGE_A(0, 0, 0); STAGE_A(0, 1, 0);
  STAGE_B(1, 0, 64); STAGE_B(1, 1, 64); STAGE_A(1, 0, 64); STAGE_A(1, 1, 64);
  asm volatile("s_waitcnt vmcnt(8)");
  SBAR; SB0;

  intx4 af[4][2], b0[2][2], b1[2][2];
  int cur = 0;

  for (int t = 0; t < nt; ++t, cur ^= 1) {
    const unsigned aC = aBase + (unsigned)cur * 32768u;
    const unsigned bC = bBase + (unsigned)cur * 32768u;
    const bool haveS = (t + 2 < nt);
    const int co2 = (t + 2) * 64;
    // ---- phase 0: Q(m0,n0) ----
    READ_A(0);
    READ_B(b0, 0);
    SBAR; SB0;
    LGKM0;
    __builtin_amdgcn_s_setprio(1);
    MFMA_Q(0, b0, 0);
    __builtin_amdgcn_s_setprio(0);
    SBAR; SB0;
    // ---- phase 1: Q(m0,n1) ----  (all Bs[cur] reads complete this phase)
    READ_B(b1, 1);
    SBAR; SB0;
    LGKM0;
    __builtin_amdgcn_s_setprio(1);
    MFMA_Q(0, b1, 1);
    __builtin_amdgcn_s_setprio(0);
    SBAR; SB0;
    // ---- phase 2: Q(m1,n0); stage B(t+2) both halves (Bs[cur] now dead) ----
    READ_A(1);
    if (haveS) { STAGE_B(cur, 0, co2); STAGE_B(cur, 1, co2); }
    SBAR; SB0;
    LGKM0;
    __builtin_amdgcn_s_setprio(1);
    MFMA_Q(1, b0, 0);
    __builtin_amdgcn_s_setprio(0);
    SBAR; SB0;
    // ---- phase 3: Q(m1,n1); stage A(t+2) both halves (As[cur] now dead) ----
    if (haveS) { STAGE_A(cur, 0, co2); STAGE_A(cur, 1, co2); }
    SBAR; SB0;
    __builtin_amdgcn_s_setprio(1);
    MFMA_Q(1, b1, 1);
    __builtin_amdgcn_s_setprio(0);
    if (t + 1 < nt) {
      if (haveS) { asm volatile("s_waitcnt vmcnt(8)"); }
      else       { asm volatile("s_waitcnt vmcnt(0)"); }
      SBAR; SB0;
    }
  }
#undef STAGE_A
#undef STAGE_B
#undef READ_A
#undef READ_B
#undef MFMA_Q

  // epilogue: row = mBase+wr*128+im*16+quad*4+r ; col = nBase+wc*64+jn*16+l15
#pragma unroll
  for (int im = 0; im < 8; ++im) {
#pragma unroll
    for (int jn = 0; jn < 4; ++jn) {
      const int col = nBase + wc * 64 + jn * 16 + l15;
      if constexpr (EPI == 0) {
        const int g = nIdx >> 2;                 // 0=s 1=r 2=z (block-uniform)
        const int colg = col & 1023;
        const float* bp = (g == 0) ? bias0 : (g == 1) ? bias1 : bias2;
        const float bv = bp[colg];
        const float* delta = (const float*)aux0;
        const float* wst   = (const float*)aux1;
        const float* hp    = (const float*)aux2;
#pragma unroll
        for (int r = 0; r < 4; ++r) {
          const int row = mBase + wr * 128 + im * 16 + quad * 4 + r;
          float v = acc[im][jn][r] + bv;
          if (g == 0) {
            v += delta[row] * wst[colg];
            ((US*)out0)[(size_t)row * ldo0 + colg] = f2bf(tanh_f(v));
          } else if (g == 1) {
            float rr = sigm(v);
            ((US*)out1)[(size_t)row * LDR + colg] =
                f2bf(rr * hp[(size_t)row * DH + colg]);
          } else {
            ((US*)out2)[(size_t)row * DH + colg] = f2bf(sigm(v));
          }
        }
      } else if constexpr (EPI == 3) {
        const float bv = bias0[col];
#pragma unroll
        for (int r = 0; r < 4; ++r) {
          const int row = mBase + wr * 128 + im * 16 + quad * 4 + r;
          float v = acc[im][jn][r] + bv;
          ((US*)out0)[(size_t)row * ldo0 + col] = f2bf(tanh_f(v));
        }
      } else {
        const float bv = bias0[col];
        const float* hp = (const float*)aux0;   // pristine f32 h_prev
        const US* Zp = (const US*)aux1;         // z, stride DH
        const US* Hp = (const US*)aux2;         // htilde, stride DH
#pragma unroll
        for (int r = 0; r < 4; ++r) {
          const int row = mBase + wr * 128 + im * 16 + quad * 4 + r;
          float v = acc[im][jn][r] + bv;
          float T = sigm(v);
          size_t o = (size_t)row * DH + col;
          float z = bf2f(Zp[o]), ht = bf2f(Hp[o]);
          float h = hp[o];
          ((float*)out0)[(size_t)row * ldo0 + col] = (1.f - z) * (T * h) + z * ht;
        }
      }
    }
  }
}

extern "C" void kernel_launch(void* const* d_in, const int* in_sizes, int n_in,
                              void* d_out, int out_size, void* d_ws, size_t ws_size,
                              hipStream_t stream) {
  const float* x_t   = (const float*)d_in[0];
  const float* delta = (const float*)d_in[1];
  const float* h_prev= (const float*)d_in[2];
  const float* W_sh  = (const float*)d_in[3];
  const float* W_sx  = (const float*)d_in[4];
  const float* W_st  = (const float*)d_in[5];
  const float* b_s   = (const float*)d_in[6];
  const float* WTh   = (const float*)d_in[7];
  const float* WTx   = (const float*)d_in[8];
  const float* WTs   = (const float*)d_in[9];
  const float* b_T   = (const float*)d_in[10];
  const float* W_rh  = (const float*)d_in[11];
  const float* W_rx  = (const float*)d_in[12];
  const float* b_r   = (const float*)d_in[13];
  const float* W_zh  = (const float*)d_in[14];
  const float* W_zx  = (const float*)d_in[15];
  const float* b_z   = (const float*)d_in[16];
  const float* W_h   = (const float*)d_in[17];
  const float* W_x   = (const float*)d_in[18];
  const float* b_    = (const float*)d_in[19];
  float* out = (float*)d_out;

  char* ws = (char*)d_ws;
  US* Ab  = (US*)ws;              size_t off = (size_t)Bsz * LDA * 2;   // 80MB
  US* RH  = (US*)(ws + off);      off += (size_t)Bsz * LDR * 2;         // 48MB
  US* Zb  = (US*)(ws + off);      off += (size_t)Bsz * DH * 2;          // 32MB
  US* HTb = (US*)(ws + off);      off += (size_t)Bsz * DH * 2;          // 32MB
  US* bWsrz = (US*)(ws + off);    off += (size_t)3072 * 1536 * 2;       // 9MB
  US* bWT   = (US*)(ws + off);    off += (size_t)DH * 2560 * 2;         // 5MB
  US* bWh   = (US*)(ws + off);    off += (size_t)DH * 1536 * 2;         // 3MB

  // Stage 0: convert
  pack_A<<<dim3(8192), 256, 0, stream>>>(h_prev, x_t, Ab, RH);
  WBatch wb;
  const int n4h = DH * DH / 4, n4x = DH * DIN / 4;   // ksh: 1024->8, 512->7
  US* bWr = bWsrz + (size_t)1024 * 1536;
  US* bWz = bWsrz + (size_t)2048 * 1536;
  wb.s[0]  = {W_sh, bWsrz, n4h, 8, 1536, 0};
  wb.s[1]  = {W_sx, bWsrz, n4x, 7, 1536, 1024};
  wb.s[2]  = {W_rh, bWr,   n4h, 8, 1536, 0};
  wb.s[3]  = {W_rx, bWr,   n4x, 7, 1536, 1024};
  wb.s[4]  = {W_zh, bWz,   n4h, 8, 1536, 0};
  wb.s[5]  = {W_zx, bWz,   n4x, 7, 1536, 1024};
  wb.s[6]  = {WTh,  bWT,   n4h, 8, 2560, 0};
  wb.s[7]  = {WTx,  bWT,   n4x, 7, 2560, 1024};
  wb.s[8]  = {WTs,  bWT,   n4h, 8, 2560, 1536};
  wb.s[9]  = {W_h,  bWh,   n4h, 8, 1536, 0};
  wb.s[10] = {W_x,  bWh,   n4x, 7, 1536, 1024};
  conv_w<<<dim3(512, 11), 256, 0, stream>>>(wb);

  // Phase 1 (fused): s -> Ab cols 1536:2560 ; r*h -> RH ; z -> Zb
  // (readers touch Ab cols 0:1536 only -> col-disjoint from the s writes)
  gemm8<0, 12><<<dim3(768), 512, 0, stream>>>(
      Ab, LDA, bWsrz, 1536, 24, b_s, b_r, b_z,
      delta, W_st, h_prev, (void*)(Ab + 1536), LDA, (void*)RH, (void*)Zb);
  // Phase 2: htilde = tanh([r*h|x] @ [W_h|W_x]^T + b) -> HTb (alias-free)
  gemm8<3, 4><<<dim3(256), 512, 0, stream>>>(
      RH, LDR, bWh, 1536, 24, b_, nullptr, nullptr,
      nullptr, nullptr, nullptr, (void*)HTb, DH, nullptr, nullptr);
  // Phase 3: T gate ([h|x|s], K=2560) + final combine -> d_out (f32)
  gemm8<4, 4><<<dim3(256), 512, 0, stream>>>(
      Ab, LDA, bWT, 2560, 40, b_T, nullptr, nullptr,
      h_prev, Zb, HTb, (void*)out, DH, nullptr, nullptr);
}

// Round 5
// 672.809 us; speedup vs baseline: 1.0239x; 1.0239x over previous
//
#include <hip/hip_runtime.h>
#include <stdint.h>

#define AS1 __attribute__((address_space(1)))
#define AS3 __attribute__((address_space(3)))

typedef unsigned short US;
typedef __bf16 bf16x8 __attribute__((ext_vector_type(8)));
typedef float f32x4 __attribute__((ext_vector_type(4)));
typedef int intx4 __attribute__((ext_vector_type(4)));

static constexpr int Bsz = 16384;
static constexpr int DIN = 512;
static constexpr int DH  = 1024;
static constexpr int LDA = 2560;   // Ab row: [h(1024) | x(512) | s(1024)]
static constexpr int LDR = 1536;   // RH row: [r*h(1024) | x(512)]

__device__ __forceinline__ US f2bf(float f) {
  unsigned u = __float_as_uint(f);
  u += 0x7fffu + ((u >> 16) & 1u);          // RNE
  return (US)(u >> 16);
}
__device__ __forceinline__ float bf2f(US u) { return __uint_as_float(((unsigned)u) << 16); }
__device__ __forceinline__ float sigm(float x) { return 1.f / (1.f + __expf(-x)); }
__device__ __forceinline__ float tanh_f(float x) { return 1.f - 2.f / (1.f + __expf(2.f * x)); }

// ds_read_b128 via inline asm: invisible to the backend waitcnt pass, so the
// K-loop's only waits are the hand-placed lgkmcnt(0) / vmcnt(0) per K-tile.
__device__ __forceinline__ intx4 dsr128(unsigned addr) {
  intx4 r;
  asm volatile("ds_read_b128 %0, %1" : "=v"(r) : "v"(addr));
  return r;
}

#define SBAR  asm volatile("s_barrier" ::: "memory")
#define SB0   __builtin_amdgcn_sched_barrier(0)
#define LGKM0 { asm volatile("s_waitcnt lgkmcnt(0)" ::: "memory"); __builtin_amdgcn_sched_barrier(0); }
#define VM0   { asm volatile("s_waitcnt vmcnt(0)" ::: "memory"); __builtin_amdgcn_sched_barrier(0); }

// ---------- convert kernels ----------
__global__ void pack_A(const float* __restrict__ h, const float* __restrict__ x,
                       US* __restrict__ Ab, US* __restrict__ RHx) {
  const int total = Bsz * 384;              // 1536 cols / 4 per item
  for (int idx = blockIdx.x * blockDim.x + threadIdx.x; idx < total;
       idx += gridDim.x * blockDim.x) {
    int row = idx / 384;
    int c = (idx - row * 384) * 4;
    const float* src = (c < DH) ? (h + (size_t)row * DH + c)
                                : (x + (size_t)row * DIN + (c - DH));
    float4 v = *(const float4*)src;
    ushort4 o;
    o.x = f2bf(v.x); o.y = f2bf(v.y); o.z = f2bf(v.z); o.w = f2bf(v.w);
    *(ushort4*)(Ab + (size_t)row * LDA + c) = o;
    if (c >= DH) *(ushort4*)(RHx + (size_t)row * LDR + c) = o;
  }
}

struct WSlot { const float* src; US* dst; int n4; int ksh; int ld; int co; };
struct WBatch { WSlot s[11]; };
__global__ void conv_w(WBatch b) {
  WSlot sl = b.s[blockIdx.y];   // uniform per block
  const int mask = (1 << sl.ksh) - 1;
  for (int i = blockIdx.x * blockDim.x + threadIdx.x; i < sl.n4;
       i += gridDim.x * blockDim.x) {
    float4 v = *(const float4*)(sl.src + (size_t)i * 4);
    ushort4 o;
    o.x = f2bf(v.x); o.y = f2bf(v.y); o.z = f2bf(v.z); o.w = f2bf(v.w);
    int r = i >> sl.ksh;
    int cc = (i & mask) * 4;
    *(ushort4*)(sl.dst + (size_t)r * sl.ld + sl.co + cc) = o;
  }
}

// ---------- 256x256 GEMM, 2-phase K-loop (m230-V0 recipe), fused epilogue ----
// 8 waves (2Mx4N), BK=64, dbuf LDS. Per K-tile: STAGE(t+1 -> buf^1) (8 DMA),
// all 24 ds_read_b128 of buf[cur], ONE lgkmcnt(0), 64-MFMA cluster, ONE
// vmcnt(0), ONE s_barrier. R4 post-mortem: 9 sync events/tile @~650cyc each
// was ~70% of tile time; this has 3.
//
// Legality: stage writes only buf^1 (not read this tile). Each wave's reads
// of buf[cur] retire (results consumed by its MFMAs) before it reaches the
// barrier; next tile's stage into buf[cur] is issued only after the barrier.
// vmcnt(0) before the barrier guarantees buf^1 fully landed for tile t+1.
//
// EPI: 0 = fused s/r/z (gate = nIdx>>2)   3 = htilde(tanh)   4 = T + combine
template <int EPI, int NBLK>
__global__ __launch_bounds__(512, 2) void gemm8(
    const US* __restrict__ A, int lda,
    const US* __restrict__ W, int ldw, int nt,
    const float* __restrict__ bias0, const float* __restrict__ bias1,
    const float* __restrict__ bias2,
    const void* aux0, const void* aux1, const void* aux2,
    void* out0, int ldo0, void* out1, void* out2) {
  __shared__ __align__(16) US As[2][256 * 64];
  __shared__ __align__(16) US Bs[2][256 * 64];

  const int tid  = threadIdx.x;
  const int lane = tid & 63;
  const int w    = tid >> 6;          // wave 0..7
  const int wr   = w >> 2;            // m half (128 rows)
  const int wc   = w & 3;             // n quarter (64 cols)
  const int quad = lane >> 4, l15 = lane & 15;
  const int sw8  = l15 & 7;
  const int lrow = lane >> 3;
  const int scc  = (lane & 7) ^ (lrow & 7);

  // XCD-aware bijective swizzle: XCD c owns m-blocks [c*8, c*8+8) x all NBLK
  // n-peers -> A tiles fetched ~once per XCD L2.
  const int p = blockIdx.x;
  const int c = p & 7, q = p >> 3;
  const int nIdx = q % NBLK, mIdx = c * 8 + q / NBLK;
  const int mBase = mIdx * 256, nBase = nIdx * 256;

  f32x4 acc[8][4];
#pragma unroll
  for (int i = 0; i < 8; i++)
#pragma unroll
    for (int j = 0; j < 4; j++) acc[i][j] = f32x4{0.f, 0.f, 0.f, 0.f};

  // LDS byte bases (low 32 bits of the generic pointer = LDS offset)
  const unsigned aBase = (unsigned)(uintptr_t)&As[0][0];
  const unsigned bBase = (unsigned)(uintptr_t)&Bs[0][0];
  const unsigned arB = (unsigned)((wr * 128 + l15) * 128);
  const unsigned brB = (unsigned)((wc * 64 + l15) * 128);
  const unsigned kc0 = (unsigned)((quad ^ sw8) * 16);

  const size_t aRowS = (size_t)(mBase + w * 8 + lrow) * lda;
  const size_t wRowS = (size_t)(nBase + w * 8 + lrow) * ldw;
  const int sccOff = scc * 8;

#define STAGE_A(d, hh, co)                                                       \
  { const US* g = A + aRowS + (size_t)(hh) * 128 * lda + (co) + sccOff;          \
    __builtin_amdgcn_global_load_lds((AS1 const void*)g,                         \
        (AS3 void*)&As[d][((hh)*128 + w * 8) * 64], 16, 0, 0);                   \
    __builtin_amdgcn_global_load_lds((AS1 const void*)(g + (size_t)64 * lda),    \
        (AS3 void*)&As[d][((hh)*128 + 64 + w * 8) * 64], 16, 0, 0); }
#define STAGE_B(d, hh, co)                                                       \
  { const US* g = W + wRowS + (size_t)(hh) * 128 * ldw + (co) + sccOff;          \
    __builtin_amdgcn_global_load_lds((AS1 const void*)g,                         \
        (AS3 void*)&Bs[d][((hh)*128 + w * 8) * 64], 16, 0, 0);                   \
    __builtin_amdgcn_global_load_lds((AS1 const void*)(g + (size_t)64 * ldw),    \
        (AS3 void*)&Bs[d][((hh)*128 + 64 + w * 8) * 64], 16, 0, 0); }

#define READ_A(AF, mh)                                                           \
  _Pragma("unroll")                                                              \
  for (int i = 0; i < 4; ++i)                                                    \
    _Pragma("unroll")                                                            \
    for (int ks = 0; ks < 2; ++ks)                                               \
      AF[i][ks] = dsr128(aC + arB + (mh)*8192u + (unsigned)i * 2048u +           \
                         (kc0 ^ (unsigned)(ks << 6)));
#define READ_B(BSET, nh)                                                         \
  _Pragma("unroll")                                                              \
  for (int j = 0; j < 2; ++j)                                                    \
    _Pragma("unroll")                                                            \
    for (int ks = 0; ks < 2; ++ks)                                               \
      BSET[j][ks] = dsr128(bC + brB + (nh)*4096u + (unsigned)j * 2048u +         \
                           (kc0 ^ (unsigned)(ks << 6)));
#define MFMA_Q(AF, mh, BSET, nh)                                                 \
  _Pragma("unroll")                                                              \
  for (int ks = 0; ks < 2; ++ks)                                                 \
    _Pragma("unroll")                                                            \
    for (int i = 0; i < 4; ++i)                                                  \
      _Pragma("unroll")                                                          \
      for (int j = 0; j < 2; ++j)                                                \
        acc[(mh)*4 + i][(nh)*2 + j] = __builtin_amdgcn_mfma_f32_16x16x32_bf16(   \
            __builtin_bit_cast(bf16x8, AF[i][ks]),                               \
            __builtin_bit_cast(bf16x8, BSET[j][ks]),                             \
            acc[(mh)*4 + i][(nh)*2 + j], 0, 0, 0);

  // ---- prologue: stage tile 0 into buf 0, drain, sync ----
  STAGE_A(0, 0, 0); STAGE_A(0, 1, 0); STAGE_B(0, 0, 0); STAGE_B(0, 1, 0);
  VM0;
  SBAR; SB0;

  intx4 af0[4][2], af1[4][2], b0[2][2], b1[2][2];
  int cur = 0;

  for (int t = 0; t < nt; ++t, cur ^= 1) {
    const unsigned aC = aBase + (unsigned)cur * 32768u;
    const unsigned bC = bBase + (unsigned)cur * 32768u;
    const int nxt = cur ^ 1;
    const int co1 = (t + 1) * 64;
    // ---- issue next-tile staging first (hides HBM under this tile's work) --
    if (t + 1 < nt) {
      STAGE_A(nxt, 0, co1); STAGE_A(nxt, 1, co1);
      STAGE_B(nxt, 0, co1); STAGE_B(nxt, 1, co1);
    }
    // ---- all fragment reads of buf[cur] (24 x ds_read_b128) ----
    READ_A(af0, 0);
    READ_A(af1, 1);
    READ_B(b0, 0);
    READ_B(b1, 1);
    LGKM0;
    // ---- 64-MFMA cluster ----
    __builtin_amdgcn_s_setprio(1);
    MFMA_Q(af0, 0, b0, 0);
    MFMA_Q(af0, 0, b1, 1);
    MFMA_Q(af1, 1, b0, 0);
    MFMA_Q(af1, 1, b1, 1);
    __builtin_amdgcn_s_setprio(0);
    SB0;
    // ---- single sync point per K-tile ----
    if (t + 1 < nt) { VM0; }
    SBAR; SB0;
  }
#undef STAGE_A
#undef STAGE_B
#undef READ_A
#undef READ_B
#undef MFMA_Q

  // epilogue: row = mBase+wr*128+im*16+quad*4+r ; col = nBase+wc*64+jn*16+l15
#pragma unroll
  for (int im = 0; im < 8; ++im) {
#pragma unroll
    for (int jn = 0; jn < 4; ++jn) {
      const int col = nBase + wc * 64 + jn * 16 + l15;
      if constexpr (EPI == 0) {
        const int g = nIdx >> 2;                 // 0=s 1=r 2=z (block-uniform)
        const int colg = col & 1023;
        const float* bp = (g == 0) ? bias0 : (g == 1) ? bias1 : bias2;
        const float bv = bp[colg];
        const float* delta = (const float*)aux0;
        const float* wst   = (const float*)aux1;
        const float* hp    = (const float*)aux2;
#pragma unroll
        for (int r = 0; r < 4; ++r) {
          const int row = mBase + wr * 128 + im * 16 + quad * 4 + r;
          float v = acc[im][jn][r] + bv;
          if (g == 0) {
            v += delta[row] * wst[colg];
            ((US*)out0)[(size_t)row * ldo0 + colg] = f2bf(tanh_f(v));
          } else if (g == 1) {
            float rr = sigm(v);
            ((US*)out1)[(size_t)row * LDR + colg] =
                f2bf(rr * hp[(size_t)row * DH + colg]);
          } else {
            ((US*)out2)[(size_t)row * DH + colg] = f2bf(sigm(v));
          }
        }
      } else if constexpr (EPI == 3) {
        const float bv = bias0[col];
#pragma unroll
        for (int r = 0; r < 4; ++r) {
          const int row = mBase + wr * 128 + im * 16 + quad * 4 + r;
          float v = acc[im][jn][r] + bv;
          ((US*)out0)[(size_t)row * ldo0 + col] = f2bf(tanh_f(v));
        }
      } else {
        const float bv = bias0[col];
        const float* hp = (const float*)aux0;   // pristine f32 h_prev
        const US* Zp = (const US*)aux1;         // z, stride DH
        const US* Hp = (const US*)aux2;         // htilde, stride DH
#pragma unroll
        for (int r = 0; r < 4; ++r) {
          const int row = mBase + wr * 128 + im * 16 + quad * 4 + r;
          float v = acc[im][jn][r] + bv;
          float T = sigm(v);
          size_t o = (size_t)row * DH + col;
          float z = bf2f(Zp[o]), ht = bf2f(Hp[o]);
          float h = hp[o];
          ((float*)out0)[(size_t)row * ldo0 + col] = (1.f - z) * (T * h) + z * ht;
        }
      }
    }
  }
}

extern "C" void kernel_launch(void* const* d_in, const int* in_sizes, int n_in,
                              void* d_out, int out_size, void* d_ws, size_t ws_size,
                              hipStream_t stream) {
  const float* x_t   = (const float*)d_in[0];
  const float* delta = (const float*)d_in[1];
  const float* h_prev= (const float*)d_in[2];
  const float* W_sh  = (const float*)d_in[3];
  const float* W_sx  = (const float*)d_in[4];
  const float* W_st  = (const float*)d_in[5];
  const float* b_s   = (const float*)d_in[6];
  const float* WTh   = (const float*)d_in[7];
  const float* WTx   = (const float*)d_in[8];
  const float* WTs   = (const float*)d_in[9];
  const float* b_T   = (const float*)d_in[10];
  const float* W_rh  = (const float*)d_in[11];
  const float* W_rx  = (const float*)d_in[12];
  const float* b_r   = (const float*)d_in[13];
  const float* W_zh  = (const float*)d_in[14];
  const float* W_zx  = (const float*)d_in[15];
  const float* b_z   = (const float*)d_in[16];
  const float* W_h   = (const float*)d_in[17];
  const float* W_x   = (const float*)d_in[18];
  const float* b_    = (const float*)d_in[19];
  float* out = (float*)d_out;

  char* ws = (char*)d_ws;
  US* Ab  = (US*)ws;              size_t off = (size_t)Bsz * LDA * 2;   // 80MB
  US* RH  = (US*)(ws + off);      off += (size_t)Bsz * LDR * 2;         // 48MB
  US* Zb  = (US*)(ws + off);      off += (size_t)Bsz * DH * 2;          // 32MB
  US* HTb = (US*)(ws + off);      off += (size_t)Bsz * DH * 2;          // 32MB
  US* bWsrz = (US*)(ws + off);    off += (size_t)3072 * 1536 * 2;       // 9MB
  US* bWT   = (US*)(ws + off);    off += (size_t)DH * 2560 * 2;         // 5MB
  US* bWh   = (US*)(ws + off);    off += (size_t)DH * 1536 * 2;         // 3MB

  // Stage 0: convert
  pack_A<<<dim3(8192), 256, 0, stream>>>(h_prev, x_t, Ab, RH);
  WBatch wb;
  const int n4h = DH * DH / 4, n4x = DH * DIN / 4;   // ksh: 1024->8, 512->7
  US* bWr = bWsrz + (size_t)1024 * 1536;
  US* bWz = bWsrz + (size_t)2048 * 1536;
  wb.s[0]  = {W_sh, bWsrz, n4h, 8, 1536, 0};
  wb.s[1]  = {W_sx, bWsrz, n4x, 7, 1536, 1024};
  wb.s[2]  = {W_rh, bWr,   n4h, 8, 1536, 0};
  wb.s[3]  = {W_rx, bWr,   n4x, 7, 1536, 1024};
  wb.s[4]  = {W_zh, bWz,   n4h, 8, 1536, 0};
  wb.s[5]  = {W_zx, bWz,   n4x, 7, 1536, 1024};
  wb.s[6]  = {WTh,  bWT,   n4h, 8, 2560, 0};
  wb.s[7]  = {WTx,  bWT,   n4x, 7, 2560, 1024};
  wb.s[8]  = {WTs,  bWT,   n4h, 8, 2560, 1536};
  wb.s[9]  = {W_h,  bWh,   n4h, 8, 1536, 0};
  wb.s[10] = {W_x,  bWh,   n4x, 7, 1536, 1024};
  conv_w<<<dim3(512, 11), 256, 0, stream>>>(wb);

  // Phase 1 (fused): s -> Ab cols 1536:2560 ; r*h -> RH ; z -> Zb
  // (readers touch Ab cols 0:1536 only -> col-disjoint from the s writes)
  gemm8<0, 12><<<dim3(768), 512, 0, stream>>>(
      Ab, LDA, bWsrz, 1536, 24, b_s, b_r, b_z,
      delta, W_st, h_prev, (void*)(Ab + 1536), LDA, (void*)RH, (void*)Zb);
  // Phase 2: htilde = tanh([r*h|x] @ [W_h|W_x]^T + b) -> HTb (alias-free)
  gemm8<3, 4><<<dim3(256), 512, 0, stream>>>(
      RH, LDR, bWh, 1536, 24, b_, nullptr, nullptr,
      nullptr, nullptr, nullptr, (void*)HTb, DH, nullptr, nullptr);
  // Phase 3: T gate ([h|x|s], K=2560) + final combine -> d_out (f32)
  gemm8<4, 4><<<dim3(256), 512, 0, stream>>>(
      Ab, LDA, bWT, 2560, 40, b_T, nullptr, nullptr,
      h_prev, Zb, HTb, (void*)out, DH, nullptr, nullptr);
}

// Round 6
// 672.507 us; speedup vs baseline: 1.0244x; 1.0004x over previous
//
#include <hip/hip_runtime.h>
#include <stdint.h>

#define AS1 __attribute__((address_space(1)))
#define AS3 __attribute__((address_space(3)))

typedef unsigned short US;
typedef __bf16 bf16x8 __attribute__((ext_vector_type(8)));
typedef float f32x4 __attribute__((ext_vector_type(4)));
typedef int intx4 __attribute__((ext_vector_type(4)));

static constexpr int Bsz = 16384;
static constexpr int DIN = 512;
static constexpr int DH  = 1024;
static constexpr int LDA = 2560;   // Ab row: [h(1024) | x(512) | s(1024)]
static constexpr int LDR = 1536;   // RH row: [r*h(1024) | x(512)]

__device__ __forceinline__ US f2bf(float f) {
  unsigned u = __float_as_uint(f);
  u += 0x7fffu + ((u >> 16) & 1u);          // RNE
  return (US)(u >> 16);
}
__device__ __forceinline__ float bf2f(US u) { return __uint_as_float(((unsigned)u) << 16); }
__device__ __forceinline__ float sigm(float x) { return 1.f / (1.f + __expf(-x)); }
__device__ __forceinline__ float tanh_f(float x) { return 1.f - 2.f / (1.f + __expf(2.f * x)); }

// ds_read_b128 via inline asm: invisible to the backend waitcnt pass.
__device__ __forceinline__ intx4 dsr128(unsigned addr) {
  intx4 r;
  asm volatile("ds_read_b128 %0, %1" : "=v"(r) : "v"(addr));
  return r;
}

// R5 post-mortem: asm s_barrier / waits with ":::memory" are treated as
// memory ops by SIInsertWaitcnts -> compiler inserts vmcnt(0) lgkmcnt(0)
// before them -> every barrier was a full drain (R1==R4==R5 perf proves it).
// m201 template: BUILTIN s_barrier + clobber-free asm waits + SB0 after waits.
#define BARR  __builtin_amdgcn_s_barrier()
#define SB0   __builtin_amdgcn_sched_barrier(0)
#define LGKM0 { asm volatile("s_waitcnt lgkmcnt(0)"); __builtin_amdgcn_sched_barrier(0); }
#define VMC8  { asm volatile("s_waitcnt vmcnt(8)"); __builtin_amdgcn_sched_barrier(0); }
#define VMC0  { asm volatile("s_waitcnt vmcnt(0)"); __builtin_amdgcn_sched_barrier(0); }

// ---------- convert kernels ----------
__global__ void pack_A(const float* __restrict__ h, const float* __restrict__ x,
                       US* __restrict__ Ab, US* __restrict__ RHx) {
  const int total = Bsz * 384;              // 1536 cols / 4 per item
  for (int idx = blockIdx.x * blockDim.x + threadIdx.x; idx < total;
       idx += gridDim.x * blockDim.x) {
    int row = idx / 384;
    int c = (idx - row * 384) * 4;
    const float* src = (c < DH) ? (h + (size_t)row * DH + c)
                                : (x + (size_t)row * DIN + (c - DH));
    float4 v = *(const float4*)src;
    ushort4 o;
    o.x = f2bf(v.x); o.y = f2bf(v.y); o.z = f2bf(v.z); o.w = f2bf(v.w);
    *(ushort4*)(Ab + (size_t)row * LDA + c) = o;
    if (c >= DH) *(ushort4*)(RHx + (size_t)row * LDR + c) = o;
  }
}

struct WSlot { const float* src; US* dst; int n4; int ksh; int ld; int co; };
struct WBatch { WSlot s[11]; };
__global__ void conv_w(WBatch b) {
  WSlot sl = b.s[blockIdx.y];   // uniform per block
  const int mask = (1 << sl.ksh) - 1;
  for (int i = blockIdx.x * blockDim.x + threadIdx.x; i < sl.n4;
       i += gridDim.x * blockDim.x) {
    float4 v = *(const float4*)(sl.src + (size_t)i * 4);
    ushort4 o;
    o.x = f2bf(v.x); o.y = f2bf(v.y); o.z = f2bf(v.z); o.w = f2bf(v.w);
    int r = i >> sl.ksh;
    int cc = (i & mask) * 4;
    *(ushort4*)(sl.dst + (size_t)r * sl.ld + sl.co + cc) = o;
  }
}

// ---------- 256x256 GEMM, counted-vmcnt 2-deep pipeline, fused epilogue -----
// 8 waves (2Mx4N), BK=64, dbuf LDS, prefetch 2 K-tiles ahead. Per K-tile:
//   24 ds_read_b128(buf[cur]) ; lgkmcnt(0) ; BARRIER(reads retired block-wide)
//   stage t+2 -> buf[cur] (8 DMA) ; 64-MFMA cluster (hides DMA issue)
//   vmcnt(8)  <- retires t+1's 8 loads, leaves t+2's 8 IN FLIGHT (never 0)
//   BARRIER
// Legality: stage into buf[cur] only after the barrier that proves every
// wave's reads of buf[cur] retired. vmcnt(8) + barrier proves buf[nxt]
// (tile t+1) fully landed before any wave reads it next iteration.
//
// EPI: 0 = fused s/r/z (gate = nIdx>>2)   3 = htilde(tanh)   4 = T + combine
template <int EPI, int NBLK>
__global__ __launch_bounds__(512, 2) void gemm8(
    const US* __restrict__ A, int lda,
    const US* __restrict__ W, int ldw, int nt,
    const float* __restrict__ bias0, const float* __restrict__ bias1,
    const float* __restrict__ bias2,
    const void* aux0, const void* aux1, const void* aux2,
    void* out0, int ldo0, void* out1, void* out2) {
  __shared__ __align__(16) US As[2][256 * 64];
  __shared__ __align__(16) US Bs[2][256 * 64];

  const int tid  = threadIdx.x;
  const int lane = tid & 63;
  const int w    = tid >> 6;          // wave 0..7
  const int wr   = w >> 2;            // m half (128 rows)
  const int wc   = w & 3;             // n quarter (64 cols)
  const int quad = lane >> 4, l15 = lane & 15;
  const int sw8  = l15 & 7;
  const int lrow = lane >> 3;
  const int scc  = (lane & 7) ^ (lrow & 7);

  // XCD-aware bijective swizzle: XCD c owns m-blocks [c*8, c*8+8) x all NBLK
  // n-peers -> A tiles fetched ~once per XCD L2.
  const int p = blockIdx.x;
  const int c = p & 7, q = p >> 3;
  const int nIdx = q % NBLK, mIdx = c * 8 + q / NBLK;
  const int mBase = mIdx * 256, nBase = nIdx * 256;

  f32x4 acc[8][4];
#pragma unroll
  for (int i = 0; i < 8; i++)
#pragma unroll
    for (int j = 0; j < 4; j++) acc[i][j] = f32x4{0.f, 0.f, 0.f, 0.f};

  // LDS byte bases (low 32 bits of the generic pointer = LDS offset)
  const unsigned aBase = (unsigned)(uintptr_t)&As[0][0];
  const unsigned bBase = (unsigned)(uintptr_t)&Bs[0][0];
  const unsigned arB = (unsigned)((wr * 128 + l15) * 128);
  const unsigned brB = (unsigned)((wc * 64 + l15) * 128);
  const unsigned kc0 = (unsigned)((quad ^ sw8) * 16);

  const size_t aRowS = (size_t)(mBase + w * 8 + lrow) * lda;
  const size_t wRowS = (size_t)(nBase + w * 8 + lrow) * ldw;
  const int sccOff = scc * 8;

#define STAGE_A(d, hh, co)                                                       \
  { const US* g = A + aRowS + (size_t)(hh) * 128 * lda + (co) + sccOff;          \
    __builtin_amdgcn_global_load_lds((AS1 const void*)g,                         \
        (AS3 void*)&As[d][((hh)*128 + w * 8) * 64], 16, 0, 0);                   \
    __builtin_amdgcn_global_load_lds((AS1 const void*)(g + (size_t)64 * lda),    \
        (AS3 void*)&As[d][((hh)*128 + 64 + w * 8) * 64], 16, 0, 0); }
#define STAGE_B(d, hh, co)                                                       \
  { const US* g = W + wRowS + (size_t)(hh) * 128 * ldw + (co) + sccOff;          \
    __builtin_amdgcn_global_load_lds((AS1 const void*)g,                         \
        (AS3 void*)&Bs[d][((hh)*128 + w * 8) * 64], 16, 0, 0);                   \
    __builtin_amdgcn_global_load_lds((AS1 const void*)(g + (size_t)64 * ldw),    \
        (AS3 void*)&Bs[d][((hh)*128 + 64 + w * 8) * 64], 16, 0, 0); }

#define READ_A(AF, mh)                                                           \
  _Pragma("unroll")                                                              \
  for (int i = 0; i < 4; ++i)                                                    \
    _Pragma("unroll")                                                            \
    for (int ks = 0; ks < 2; ++ks)                                               \
      AF[i][ks] = dsr128(aC + arB + (mh)*8192u + (unsigned)i * 2048u +           \
                         (kc0 ^ (unsigned)(ks << 6)));
#define READ_B(BSET, nh)                                                         \
  _Pragma("unroll")                                                              \
  for (int j = 0; j < 2; ++j)                                                    \
    _Pragma("unroll")                                                            \
    for (int ks = 0; ks < 2; ++ks)                                               \
      BSET[j][ks] = dsr128(bC + brB + (nh)*4096u + (unsigned)j * 2048u +         \
                           (kc0 ^ (unsigned)(ks << 6)));
#define MFMA_Q(AF, mh, BSET, nh)                                                 \
  _Pragma("unroll")                                                              \
  for (int ks = 0; ks < 2; ++ks)                                                 \
    _Pragma("unroll")                                                            \
    for (int i = 0; i < 4; ++i)                                                  \
      _Pragma("unroll")                                                          \
      for (int j = 0; j < 2; ++j)                                                \
        acc[(mh)*4 + i][(nh)*2 + j] = __builtin_amdgcn_mfma_f32_16x16x32_bf16(   \
            __builtin_bit_cast(bf16x8, AF[i][ks]),                               \
            __builtin_bit_cast(bf16x8, BSET[j][ks]),                             \
            acc[(mh)*4 + i][(nh)*2 + j], 0, 0, 0);

  // ---- prologue: stage tile0->buf0 and tile1->buf1; retire tile0 only ----
  STAGE_A(0, 0, 0); STAGE_A(0, 1, 0); STAGE_B(0, 0, 0); STAGE_B(0, 1, 0);
  STAGE_A(1, 0, 64); STAGE_A(1, 1, 64); STAGE_B(1, 0, 64); STAGE_B(1, 1, 64);
  VMC8;
  BARR;

  intx4 af0[4][2], af1[4][2], b0[2][2], b1[2][2];
  int cur = 0;

  for (int t = 0; t < nt; ++t, cur ^= 1) {
    const unsigned aC = aBase + (unsigned)cur * 32768u;
    const unsigned bC = bBase + (unsigned)cur * 32768u;
    const int co2 = (t + 2) * 64;
    // ---- all fragment reads of buf[cur] (24 x ds_read_b128) ----
    READ_A(af0, 0);
    READ_A(af1, 1);
    READ_B(b0, 0);
    READ_B(b1, 1);
    LGKM0;
    BARR;                       // block-wide: all reads of buf[cur] retired
    // ---- stage tile t+2 into buf[cur] (now dead), then compute ----
    if (t + 2 < nt) {
      STAGE_A(cur, 0, co2); STAGE_A(cur, 1, co2);
      STAGE_B(cur, 0, co2); STAGE_B(cur, 1, co2);
    }
    __builtin_amdgcn_s_setprio(1);
    MFMA_Q(af0, 0, b0, 0);
    MFMA_Q(af0, 0, b1, 1);
    MFMA_Q(af1, 1, b0, 0);
    MFMA_Q(af1, 1, b1, 1);
    __builtin_amdgcn_s_setprio(0);
    // ---- boundary: retire t+1, keep t+2 in flight (never vmcnt(0)) ----
    if (t + 1 < nt) {
      if (t + 2 < nt) { VMC8; } else { VMC0; }
      BARR;
    }
  }
#undef STAGE_A
#undef STAGE_B
#undef READ_A
#undef READ_B
#undef MFMA_Q

  // epilogue: row = mBase+wr*128+im*16+quad*4+r ; col = nBase+wc*64+jn*16+l15
#pragma unroll
  for (int im = 0; im < 8; ++im) {
#pragma unroll
    for (int jn = 0; jn < 4; ++jn) {
      const int col = nBase + wc * 64 + jn * 16 + l15;
      if constexpr (EPI == 0) {
        const int g = nIdx >> 2;                 // 0=s 1=r 2=z (block-uniform)
        const int colg = col & 1023;
        const float* bp = (g == 0) ? bias0 : (g == 1) ? bias1 : bias2;
        const float bv = bp[colg];
        const float* delta = (const float*)aux0;
        const float* wst   = (const float*)aux1;
        const float* hp    = (const float*)aux2;
#pragma unroll
        for (int r = 0; r < 4; ++r) {
          const int row = mBase + wr * 128 + im * 16 + quad * 4 + r;
          float v = acc[im][jn][r] + bv;
          if (g == 0) {
            v += delta[row] * wst[colg];
            ((US*)out0)[(size_t)row * ldo0 + colg] = f2bf(tanh_f(v));
          } else if (g == 1) {
            float rr = sigm(v);
            ((US*)out1)[(size_t)row * LDR + colg] =
                f2bf(rr * hp[(size_t)row * DH + colg]);
          } else {
            ((US*)out2)[(size_t)row * DH + colg] = f2bf(sigm(v));
          }
        }
      } else if constexpr (EPI == 3) {
        const float bv = bias0[col];
#pragma unroll
        for (int r = 0; r < 4; ++r) {
          const int row = mBase + wr * 128 + im * 16 + quad * 4 + r;
          float v = acc[im][jn][r] + bv;
          ((US*)out0)[(size_t)row * ldo0 + col] = f2bf(tanh_f(v));
        }
      } else {
        const float bv = bias0[col];
        const float* hp = (const float*)aux0;   // pristine f32 h_prev
        const US* Zp = (const US*)aux1;         // z, stride DH
        const US* Hp = (const US*)aux2;         // htilde, stride DH
#pragma unroll
        for (int r = 0; r < 4; ++r) {
          const int row = mBase + wr * 128 + im * 16 + quad * 4 + r;
          float v = acc[im][jn][r] + bv;
          float T = sigm(v);
          size_t o = (size_t)row * DH + col;
          float z = bf2f(Zp[o]), ht = bf2f(Hp[o]);
          float h = hp[o];
          ((float*)out0)[(size_t)row * ldo0 + col] = (1.f - z) * (T * h) + z * ht;
        }
      }
    }
  }
}

extern "C" void kernel_launch(void* const* d_in, const int* in_sizes, int n_in,
                              void* d_out, int out_size, void* d_ws, size_t ws_size,
                              hipStream_t stream) {
  const float* x_t   = (const float*)d_in[0];
  const float* delta = (const float*)d_in[1];
  const float* h_prev= (const float*)d_in[2];
  const float* W_sh  = (const float*)d_in[3];
  const float* W_sx  = (const float*)d_in[4];
  const float* W_st  = (const float*)d_in[5];
  const float* b_s   = (const float*)d_in[6];
  const float* WTh   = (const float*)d_in[7];
  const float* WTx   = (const float*)d_in[8];
  const float* WTs   = (const float*)d_in[9];
  const float* b_T   = (const float*)d_in[10];
  const float* W_rh  = (const float*)d_in[11];
  const float* W_rx  = (const float*)d_in[12];
  const float* b_r   = (const float*)d_in[13];
  const float* W_zh  = (const float*)d_in[14];
  const float* W_zx  = (const float*)d_in[15];
  const float* b_z   = (const float*)d_in[16];
  const float* W_h   = (const float*)d_in[17];
  const float* W_x   = (const float*)d_in[18];
  const float* b_    = (const float*)d_in[19];
  float* out = (float*)d_out;

  char* ws = (char*)d_ws;
  US* Ab  = (US*)ws;              size_t off = (size_t)Bsz * LDA * 2;   // 80MB
  US* RH  = (US*)(ws + off);      off += (size_t)Bsz * LDR * 2;         // 48MB
  US* Zb  = (US*)(ws + off);      off += (size_t)Bsz * DH * 2;          // 32MB
  US* HTb = (US*)(ws + off);      off += (size_t)Bsz * DH * 2;          // 32MB
  US* bWsrz = (US*)(ws + off);    off += (size_t)3072 * 1536 * 2;       // 9MB
  US* bWT   = (US*)(ws + off);    off += (size_t)DH * 2560 * 2;         // 5MB
  US* bWh   = (US*)(ws + off);    off += (size_t)DH * 1536 * 2;         // 3MB

  // Stage 0: convert
  pack_A<<<dim3(8192), 256, 0, stream>>>(h_prev, x_t, Ab, RH);
  WBatch wb;
  const int n4h = DH * DH / 4, n4x = DH * DIN / 4;   // ksh: 1024->8, 512->7
  US* bWr = bWsrz + (size_t)1024 * 1536;
  US* bWz = bWsrz + (size_t)2048 * 1536;
  wb.s[0]  = {W_sh, bWsrz, n4h, 8, 1536, 0};
  wb.s[1]  = {W_sx, bWsrz, n4x, 7, 1536, 1024};
  wb.s[2]  = {W_rh, bWr,   n4h, 8, 1536, 0};
  wb.s[3]  = {W_rx, bWr,   n4x, 7, 1536, 1024};
  wb.s[4]  = {W_zh, bWz,   n4h, 8, 1536, 0};
  wb.s[5]  = {W_zx, bWz,   n4x, 7, 1536, 1024};
  wb.s[6]  = {WTh,  bWT,   n4h, 8, 2560, 0};
  wb.s[7]  = {WTx,  bWT,   n4x, 7, 2560, 1024};
  wb.s[8]  = {WTs,  bWT,   n4h, 8, 2560, 1536};
  wb.s[9]  = {W_h,  bWh,   n4h, 8, 1536, 0};
  wb.s[10] = {W_x,  bWh,   n4x, 7, 1536, 1024};
  conv_w<<<dim3(512, 11), 256, 0, stream>>>(wb);

  // Phase 1 (fused): s -> Ab cols 1536:2560 ; r*h -> RH ; z -> Zb
  // (readers touch Ab cols 0:1536 only -> col-disjoint from the s writes)
  gemm8<0, 12><<<dim3(768), 512, 0, stream>>>(
      Ab, LDA, bWsrz, 1536, 24, b_s, b_r, b_z,
      delta, W_st, h_prev, (void*)(Ab + 1536), LDA, (void*)RH, (void*)Zb);
  // Phase 2: htilde = tanh([r*h|x] @ [W_h|W_x]^T + b) -> HTb (alias-free)
  gemm8<3, 4><<<dim3(256), 512, 0, stream>>>(
      RH, LDR, bWh, 1536, 24, b_, nullptr, nullptr,
      nullptr, nullptr, nullptr, (void*)HTb, DH, nullptr, nullptr);
  // Phase 3: T gate ([h|x|s], K=2560) + final combine -> d_out (f32)
  gemm8<4, 4><<<dim3(256), 512, 0, stream>>>(
      Ab, LDA, bWT, 2560, 40, b_T, nullptr, nullptr,
      h_prev, Zb, HTb, (void*)out, DH, nullptr, nullptr);
}